// Round 2
// baseline (21999.815 us; speedup 1.0000x reference)
//
#include <hip/hip_runtime.h>

// Problem constants (B,T,S,L,D_IN,OUT,W = 256,512,256,36,8,10,256)
#define Bb   256
#define Tt   512
#define Ss   256
#define Ll   36
#define DIN  8
#define OUTd 10
#define Ww   256
#define SLn  9216

typedef __attribute__((ext_vector_type(8))) short short8;
typedef __attribute__((ext_vector_type(4))) float f32x4;
typedef __attribute__((ext_vector_type(4))) unsigned short us4;

__device__ __forceinline__ unsigned short f2bf(float f) {
    union { float f; unsigned int u; } v; v.f = f;
    unsigned int r = v.u + 0x7fffu + ((v.u >> 16) & 1u);   // RNE
    return (unsigned short)(r >> 16);
}
__device__ __forceinline__ float bf2f(unsigned short u) {
    union { unsigned int u; float f; } v; v.u = ((unsigned int)u) << 16;
    return v.f;
}
// jax.nn.softplus = max(x,0) + log1p(exp(-|x|))
__device__ __forceinline__ float sp_f(float x) {
    return fmaxf(x, 0.f) + __logf(1.f + __expf(-fabsf(x)));
}
__device__ __forceinline__ float tanh_f(float x) {
    float e = __expf(2.f * x);            // +inf/0 saturate correctly
    return 1.f - 2.f / (e + 1.f);
}

// ---------------- fp32 -> bf16 hi/lo split cast (weights, once per launch) ----------------
__global__ __launch_bounds__(256) void castk2(const float* __restrict__ s,
                                              unsigned short* __restrict__ dh,
                                              unsigned short* __restrict__ dl, int n) {
    int i = (blockIdx.x * 256 + threadIdx.x) * 4;
    if (i + 3 < n) {
#pragma unroll
        for (int q = 0; q < 4; ++q) {
            float v = s[i + q];
            unsigned short hi = f2bf(v);
            dh[i + q] = hi;
            dl[i + q] = f2bf(v - bf2f(hi));
        }
    }
}

// ---------------- initial-condition MLP: x0[B,8] -> h[B,256] (fp32 exact) ----------------
__global__ __launch_bounds__(256) void init_kernel(
    const float* __restrict__ x0,
    const float* __restrict__ iW1, const float* __restrict__ ib1,
    const float* __restrict__ iW2, const float* __restrict__ ib2,
    const float* __restrict__ iW3, const float* __restrict__ ib3,
    float* __restrict__ h) {
    __shared__ float x0s[32][DIN];
    __shared__ float h1[32 * 257];
    __shared__ float h2[32 * 257];
    const int tid = threadIdx.x;
    const int b0 = blockIdx.x * 32;
    x0s[tid >> 3][tid & 7] = x0[(b0 + (tid >> 3)) * DIN + (tid & 7)];
    __syncthreads();
    const int j = tid; // output column
    {
        float w[DIN];
#pragma unroll
        for (int k = 0; k < DIN; ++k) w[k] = iW1[j * DIN + k];
        float bias = ib1[j];
        for (int r = 0; r < 32; ++r) {
            float acc = bias;
#pragma unroll
            for (int k = 0; k < DIN; ++k) acc += x0s[r][k] * w[k];
            h1[r * 257 + j] = sp_f(acc);
        }
    }
    __syncthreads();
    {
        float bias = ib2[j];
        for (int rb = 0; rb < 4; ++rb) {
            float a8[8];
#pragma unroll
            for (int rr = 0; rr < 8; ++rr) a8[rr] = bias;
            for (int k = 0; k < 256; ++k) {
                float wv = iW2[j * 256 + k];
#pragma unroll
                for (int rr = 0; rr < 8; ++rr) a8[rr] += h1[(rb * 8 + rr) * 257 + k] * wv;
            }
#pragma unroll
            for (int rr = 0; rr < 8; ++rr) h2[(rb * 8 + rr) * 257 + j] = sp_f(a8[rr]);
        }
    }
    __syncthreads();
    {
        float bias = ib3[j];
        for (int rb = 0; rb < 4; ++rb) {
            float a8[8];
#pragma unroll
            for (int rr = 0; rr < 8; ++rr) a8[rr] = bias;
            for (int k = 0; k < 256; ++k) {
                float wv = iW3[j * 256 + k];
#pragma unroll
                for (int rr = 0; rr < 8; ++rr) a8[rr] += h2[(rb * 8 + rr) * 257 + k] * wv;
            }
#pragma unroll
            for (int rr = 0; rr < 8; ++rr) h[(b0 + rb * 8 + rr) * 256 + j] = a8[rr];
        }
    }
}

// ---------------- per-step: z1 = sp(h W1^T), z2 = sp(z1 W2^T), fused readout of hidden_t ----
// bf16x2 emulation: every matmul = Ah*Bh + Ah*Bl + Al*Bh (3 MFMAs), per-term rel err ~2^-17.
// grid 16 blocks x 256 thr; block handles 16 batch rows; MFMA 16x16x32 bf16.
// A-frag: A[m=lane&15][k=(lane>>4)*8+j]; B-frag: row n=lane&15 of row-major [N][K] weights.
// C/D: col=lane&15, row=(lane>>4)*4+reg
__global__ __launch_bounds__(256) void ab_kernel(
    const float* __restrict__ h,
    const unsigned short* __restrict__ w1h, const unsigned short* __restrict__ w1l,
    const float* __restrict__ vb1,
    const unsigned short* __restrict__ w2h, const unsigned short* __restrict__ w2l,
    const float* __restrict__ vb2,
    unsigned short* __restrict__ z2gh, unsigned short* __restrict__ z2gl,
    const float* __restrict__ roW, const float* __restrict__ rob,
    float* __restrict__ out, int t) {
    __shared__ short hlh[16 * 264];
    __shared__ short hll[16 * 264];
    __shared__ short z1h[16 * 264];
    __shared__ short z1l[16 * 264];
    const int tid = threadIdx.x;
    const int b0 = blockIdx.x * 16;
    // stage h (fp32 -> hi/lo bf16 split)
    for (int i = tid; i < 16 * 256; i += 256) {
        int r = i >> 8, c = i & 255;
        float v = h[(b0 + r) * 256 + c];
        unsigned short hi = f2bf(v);
        hlh[r * 264 + c] = (short)hi;
        hll[r * 264 + c] = (short)f2bf(v - bf2f(hi));
    }
    __syncthreads();
    const int w = tid >> 6, lane = tid & 63, quad = lane >> 4, l15 = lane & 15;
    const f32x4 zero4 = {0.f, 0.f, 0.f, 0.f};
    // ---- stage 1: z1 ----
    {
        f32x4 acc[4] = {zero4, zero4, zero4, zero4};
        for (int k0 = 0; k0 < 256; k0 += 32) {
            short8 ah = *(const short8*)(const void*)&hlh[l15 * 264 + k0 + quad * 8];
            short8 al = *(const short8*)(const void*)&hll[l15 * 264 + k0 + quad * 8];
#pragma unroll
            for (int j = 0; j < 4; ++j) {
                int n = (4 * w + j) * 16 + l15;
                short8 bh = *(const short8*)(const void*)(w1h + n * 256 + k0 + quad * 8);
                short8 bl = *(const short8*)(const void*)(w1l + n * 256 + k0 + quad * 8);
                acc[j] = __builtin_amdgcn_mfma_f32_16x16x32_bf16(ah, bh, acc[j], 0, 0, 0);
                acc[j] = __builtin_amdgcn_mfma_f32_16x16x32_bf16(ah, bl, acc[j], 0, 0, 0);
                acc[j] = __builtin_amdgcn_mfma_f32_16x16x32_bf16(al, bh, acc[j], 0, 0, 0);
            }
        }
#pragma unroll
        for (int j = 0; j < 4; ++j) {
            int n = (4 * w + j) * 16 + l15;
            float bias = vb1[n];
#pragma unroll
            for (int r = 0; r < 4; ++r) {
                int row = quad * 4 + r;
                float v = sp_f(acc[j][r] + bias);
                unsigned short hi = f2bf(v);
                z1h[row * 264 + n] = (short)hi;
                z1l[row * 264 + n] = (short)f2bf(v - bf2f(hi));
            }
        }
    }
    __syncthreads();
    // ---- stage 2: z2 -> global hi/lo bf16 ----
    {
        f32x4 acc[4] = {zero4, zero4, zero4, zero4};
        for (int k0 = 0; k0 < 256; k0 += 32) {
            short8 ah = *(const short8*)(const void*)&z1h[l15 * 264 + k0 + quad * 8];
            short8 al = *(const short8*)(const void*)&z1l[l15 * 264 + k0 + quad * 8];
#pragma unroll
            for (int j = 0; j < 4; ++j) {
                int n = (4 * w + j) * 16 + l15;
                short8 bh = *(const short8*)(const void*)(w2h + n * 256 + k0 + quad * 8);
                short8 bl = *(const short8*)(const void*)(w2l + n * 256 + k0 + quad * 8);
                acc[j] = __builtin_amdgcn_mfma_f32_16x16x32_bf16(ah, bh, acc[j], 0, 0, 0);
                acc[j] = __builtin_amdgcn_mfma_f32_16x16x32_bf16(ah, bl, acc[j], 0, 0, 0);
                acc[j] = __builtin_amdgcn_mfma_f32_16x16x32_bf16(al, bh, acc[j], 0, 0, 0);
            }
        }
#pragma unroll
        for (int j = 0; j < 4; ++j) {
            int n = (4 * w + j) * 16 + l15;
            float bias = vb2[n];
#pragma unroll
            for (int r = 0; r < 4; ++r) {
                int row = quad * 4 + r;
                float v = sp_f(acc[j][r] + bias);
                unsigned short hi = f2bf(v);
                z2gh[(b0 + row) * 256 + n] = hi;
                z2gl[(b0 + row) * 256 + n] = f2bf(v - bf2f(hi));
            }
        }
    }
    // ---- fused readout of hidden_t (fp32 h, exact) : out[b, t, :] ----
    for (int idx = tid; idx < 16 * OUTd; idx += 256) {
        int bl = idx / OUTd, o = idx - bl * OUTd;
        float acc = rob[o];
        const float* hp = h + (b0 + bl) * 256;
        const float* wp = roW + o * 256;
        for (int s = 0; s < 256; ++s) acc += hp[s] * wp[s];
        out[((long)(b0 + bl) * 513 + t) * OUTd + o] = acc;
    }
}

// ---------------- per-step big stage: m = tanh(z2 W3^T + b3); h += einsum(m, ls) ----------------
// grid 512 blocks (8 batch-chunks x 64 n-slices of 144 = 4 s), 192 thr (3 waves, 3 n-tiles each).
// blockIdx = bch*64 + nsl: same nsl -> same idx%8 -> same XCD -> W3 slice stays in that XCD's L2.
__global__ __launch_bounds__(192) void c_kernel(
    const unsigned short* __restrict__ z2gh, const unsigned short* __restrict__ z2gl,
    const unsigned short* __restrict__ w3h, const unsigned short* __restrict__ w3l,
    const float* __restrict__ vb3,
    const float* __restrict__ logsigs,
    float* __restrict__ h, int t) {
    __shared__ short z2sh[32 * 264];
    __shared__ short z2sl[32 * 264];
    __shared__ float lss[32 * 36];
    __shared__ float ml[32 * 148];
    __shared__ float b3s[144];
    const int tid = threadIdx.x;
    const int bch = blockIdx.x >> 6, nsl = blockIdx.x & 63;
    const int b0 = bch * 32, n0 = nsl * 144, s0 = nsl * 4;
    // stage z2 hi/lo tiles [32][256] bf16 (padded 264)
    for (int i = tid; i < 2048; i += 192) {
        int j = i * 4;
        int r = j >> 8, c = j & 255;
        *(us4*)(void*)&z2sh[r * 264 + c] = *(const us4*)(const void*)(z2gh + (b0 + r) * 256 + c);
        *(us4*)(void*)&z2sl[r * 264 + c] = *(const us4*)(const void*)(z2gl + (b0 + r) * 256 + c);
    }
    // stage logsigs[:, t, :] tile [32][36]
    for (int i = tid; i < 32 * Ll; i += 192) {
        int r = i / Ll, l = i - r * Ll;
        lss[i] = logsigs[((long)(b0 + r) * Tt + t) * Ll + l];
    }
    if (tid < 144) b3s[tid] = vb3[n0 + tid];
    __syncthreads();
    const int w = tid >> 6, lane = tid & 63, quad = lane >> 4, l15 = lane & 15;
    const int ntb = 3 * w; // each of 3 waves owns 3 n-tiles (n-tile = 16 cols)
    const f32x4 zero4 = {0.f, 0.f, 0.f, 0.f};
    f32x4 acc[2][3];
#pragma unroll
    for (int mt = 0; mt < 2; ++mt)
#pragma unroll
        for (int nt = 0; nt < 3; ++nt) acc[mt][nt] = zero4;
    for (int k0 = 0; k0 < 256; k0 += 32) {
        short8 ah[2], al[2];
#pragma unroll
        for (int mt = 0; mt < 2; ++mt) {
            ah[mt] = *(const short8*)(const void*)&z2sh[(mt * 16 + l15) * 264 + k0 + quad * 8];
            al[mt] = *(const short8*)(const void*)&z2sl[(mt * 16 + l15) * 264 + k0 + quad * 8];
        }
#pragma unroll
        for (int nt = 0; nt < 3; ++nt) {
            long n = n0 + (ntb + nt) * 16 + l15;
            short8 bh = *(const short8*)(const void*)(w3h + n * 256 + k0 + quad * 8);
            short8 bl = *(const short8*)(const void*)(w3l + n * 256 + k0 + quad * 8);
#pragma unroll
            for (int mt = 0; mt < 2; ++mt) {
                acc[mt][nt] = __builtin_amdgcn_mfma_f32_16x16x32_bf16(ah[mt], bh, acc[mt][nt], 0, 0, 0);
                acc[mt][nt] = __builtin_amdgcn_mfma_f32_16x16x32_bf16(ah[mt], bl, acc[mt][nt], 0, 0, 0);
                acc[mt][nt] = __builtin_amdgcn_mfma_f32_16x16x32_bf16(al[mt], bh, acc[mt][nt], 0, 0, 0);
            }
        }
    }
    // epilogue: tanh -> ml[row][nl]
#pragma unroll
    for (int nt = 0; nt < 3; ++nt) {
        int nl = (ntb + nt) * 16 + l15;
        float bias = b3s[nl];
#pragma unroll
        for (int mt = 0; mt < 2; ++mt) {
#pragma unroll
            for (int r = 0; r < 4; ++r) {
                int row = mt * 16 + quad * 4 + r;
                ml[row * 148 + nl] = tanh_f(acc[mt][nt][r] + bias);
            }
        }
    }
    __syncthreads();
    // l-contraction: h[b, s0+sr] += sum_l ml[brow][sr*36+l] * lss[brow][l]
    for (int i = tid; i < 128; i += 192) {
        int brow = i >> 2, sr = i & 3;
        const f32x4* mp = (const f32x4*)(const void*)&ml[brow * 148 + sr * 36];
        const f32x4* lp = (const f32x4*)(const void*)&lss[brow * 36];
        float acc = 0.f;
#pragma unroll
        for (int q = 0; q < 9; ++q) {
            f32x4 m4 = mp[q], l4 = lp[q];
            acc += m4[0] * l4[0] + m4[1] * l4[1] + m4[2] * l4[2] + m4[3] * l4[3];
        }
        int gi = (b0 + brow) * 256 + s0 + sr;
        h[gi] += acc;   // exclusive (b,s) per block
    }
}

// ---------------- final readout: out[:, 512, :] ----------------
__global__ __launch_bounds__(256) void readout_last(
    const float* __restrict__ h, const float* __restrict__ roW,
    const float* __restrict__ rob, float* __restrict__ out) {
    const int tid = threadIdx.x;
    const int b0 = blockIdx.x * 32;
    for (int idx = tid; idx < 32 * OUTd; idx += 256) {
        int bl = idx / OUTd, o = idx - bl * OUTd;
        float acc = rob[o];
        const float* hp = h + (b0 + bl) * 256;
        const float* wp = roW + o * 256;
        for (int s = 0; s < 256; ++s) acc += hp[s] * wp[s];
        out[((long)(b0 + bl) * 513 + Tt) * OUTd + o] = acc;
    }
}

extern "C" void kernel_launch(void* const* d_in, const int* in_sizes, int n_in,
                              void* d_out, int out_size, void* d_ws, size_t ws_size,
                              hipStream_t stream) {
    const float* x0      = (const float*)d_in[0];
    const float* logsigs = (const float*)d_in[1];
    const float* iW1 = (const float*)d_in[2];
    const float* ib1 = (const float*)d_in[3];
    const float* iW2 = (const float*)d_in[4];
    const float* ib2 = (const float*)d_in[5];
    const float* iW3 = (const float*)d_in[6];
    const float* ib3 = (const float*)d_in[7];
    const float* vW1 = (const float*)d_in[8];
    const float* vb1 = (const float*)d_in[9];
    const float* vW2 = (const float*)d_in[10];
    const float* vb2 = (const float*)d_in[11];
    const float* vW3 = (const float*)d_in[12];
    const float* vb3 = (const float*)d_in[13];
    const float* roW = (const float*)d_in[14];
    const float* rob = (const float*)d_in[15];
    float* out = (float*)d_out;

    char* p = (char*)d_ws;
    float* h             = (float*)p;                         // 262144 B
    unsigned short* z2gh = (unsigned short*)(p + 262144);     // 131072 B
    unsigned short* z2gl = (unsigned short*)(p + 393216);     // 131072 B
    unsigned short* w1h  = (unsigned short*)(p + 524288);     // 131072 B
    unsigned short* w1l  = (unsigned short*)(p + 655360);     // 131072 B
    unsigned short* w2h  = (unsigned short*)(p + 786432);     // 131072 B
    unsigned short* w2l  = (unsigned short*)(p + 917504);     // 131072 B
    unsigned short* w3h  = (unsigned short*)(p + 1048576);    // 4718592 B
    unsigned short* w3l  = (unsigned short*)(p + 5767168);    // 4718592 B  (total 10 MB)

    castk2<<<dim3(64),   dim3(256), 0, stream>>>(vW1, w1h, w1l, 65536);
    castk2<<<dim3(64),   dim3(256), 0, stream>>>(vW2, w2h, w2l, 65536);
    castk2<<<dim3(2304), dim3(256), 0, stream>>>(vW3, w3h, w3l, 2359296);
    init_kernel<<<dim3(8), dim3(256), 0, stream>>>(x0, iW1, ib1, iW2, ib2, iW3, ib3, h);

    for (int t = 0; t < Tt; ++t) {
        ab_kernel<<<dim3(16), dim3(256), 0, stream>>>(h, w1h, w1l, vb1, w2h, w2l, vb2,
                                                      z2gh, z2gl, roW, rob, out, t);
        c_kernel<<<dim3(512), dim3(192), 0, stream>>>(z2gh, z2gl, w3h, w3l, vb3, logsigs, h, t);
    }
    readout_last<<<dim3(8), dim3(256), 0, stream>>>(h, roW, rob, out);
}